// Round 1
// baseline (262.544 us; speedup 1.0000x reference)
//
#include <hip/hip_runtime.h>
#include <hip/hip_bf16.h>
#include <stdint.h>

// VectorQuantizer on MI355X.
//   z: (8,256,32,32) f32  -> rows = 8192, K = 256
//   embed_w: (16384,256) f32
// out: z_q (2097152 f32) + loss (1 f32)

typedef __attribute__((ext_vector_type(8))) short bf16x8;
typedef __attribute__((ext_vector_type(8))) unsigned short ushort8v;
typedef __attribute__((ext_vector_type(4))) float f32x4;

__device__ __forceinline__ unsigned short f2bf(float f) {
  unsigned u = __float_as_uint(f);
  return (unsigned short)((u + 0x7FFFu + ((u >> 16) & 1u)) >> 16);
}

typedef const __attribute__((address_space(1))) unsigned char* gas1;
typedef __attribute__((address_space(3))) unsigned char* las3;
__device__ __forceinline__ void cp16(const void* g, void* l) {
  __builtin_amdgcn_global_load_lds((gas1)g, (las3)l, 16, 0, 0);
}

// ---------------- P1: z (8,256,1024) f32 -> z_prep blocked bf16 ----------------
// layout: [mt 64][ks 8][kg 4][row 128][8 elems]  (elem = ushort bf16)
__global__ void k_prep_z(const float* __restrict__ z, unsigned short* __restrict__ zp) {
  __shared__ float tile[32][129];
  int bid = blockIdx.x;
  int b = bid >> 6, ct = (bid >> 3) & 7, hwt = bid & 7;
  int t = threadIdx.x;
  const float* src = z + b * 262144 + ct * 32 * 1024 + hwt * 128;
#pragma unroll
  for (int it = 0; it < 16; ++it) {
    int e = it * 256 + t;
    int cl = e >> 7, hl = e & 127;
    tile[cl][hl] = src[cl * 1024 + hl];           // coalesced along hl
  }
  __syncthreads();
  int mt = b * 8 + hwt;
  unsigned short* dst = zp + mt * 32768 + ct * 4096;  // ct == kstep
#pragma unroll
  for (int it = 0; it < 2; ++it) {
    int cell = it * 256 + t;
    int kg = cell >> 7, r = cell & 127;
    ushort8v v;
#pragma unroll
    for (int j = 0; j < 8; ++j) v[j] = f2bf(tile[kg * 8 + j][r]);
    *(ushort8v*)(dst + cell * 8) = v;             // coalesced 16B
  }
}

// ---------------- P2: embed (16384,256) f32 -> e_prep blocked bf16 -------------
// layout: [nb 128][ks 8][kg 4][col 128][8 elems]
__global__ void k_prep_e(const float* __restrict__ ew, unsigned short* __restrict__ ep) {
  int t = threadIdx.x;
  int n0 = blockIdx.x * 32;
  int rowl = t >> 3;
  int n = n0 + rowl;
  int nb = n >> 7, col = n & 127;
#pragma unroll
  for (int it = 0; it < 4; ++it) {
    int cellk = (t & 7) + it * 8;
    const float4 x = *(const float4*)(ew + n * 256 + cellk * 8);
    const float4 y = *(const float4*)(ew + n * 256 + cellk * 8 + 4);
    int ks = cellk >> 2, kg = cellk & 3;
    ushort8v v;
    v[0] = f2bf(x.x); v[1] = f2bf(x.y); v[2] = f2bf(x.z); v[3] = f2bf(x.w);
    v[4] = f2bf(y.x); v[5] = f2bf(y.y); v[6] = f2bf(y.z); v[7] = f2bf(y.w);
    *(ushort8v*)(ep + nb * 32768 + ks * 4096 + kg * 1024 + col * 8) = v;
  }
}

// ---------------- P3: h2[n] = 0.5*||e_n||^2 ------------------------------------
__global__ void k_norm(const float* __restrict__ ew, float* __restrict__ h2) {
  int t = threadIdx.x;
  int wv = t >> 6, lane = t & 63;
  int n = blockIdx.x * 4 + wv;
  float4 v = *(const float4*)(ew + n * 256 + lane * 4);
  float s = v.x * v.x + v.y * v.y + v.z * v.z + v.w * v.w;
#pragma unroll
  for (int off = 32; off; off >>= 1) s += __shfl_xor(s, off);
  if (lane == 0) h2[n] = 0.5f * s;
}

// ---------------- Main: fused GEMM + per-row argmax ----------------------------
// grid (8 seg, 64 mt), 256 threads. Wave w owns rows [w*32, w*32+32) of the
// 128-row M-tile, scanning all 2048 cols of its segment in 16 chunks of 128.
// A (128x256 bf16) lives in 16 reg fragments per lane; B double-buffered in LDS.
__global__ __launch_bounds__(256, 2) void k_main(
    const unsigned short* __restrict__ zp, const unsigned short* __restrict__ ep,
    const float* __restrict__ h2, int2* __restrict__ partial) {
  __shared__ unsigned char bLds[2][8192];
  int seg = blockIdx.x;   // 0..7  -> XCD-affine for L2 locality
  int mt = blockIdx.y;    // 0..63
  int t = threadIdx.x, wv = t >> 6, lane = t & 63;
  int l15 = lane & 15, kg = lane >> 4;

  // A tile -> registers: av[m*8+ks], 16B fragments
  bf16x8 av[16];
  const unsigned short* abase = zp + mt * 32768;
#pragma unroll
  for (int m = 0; m < 2; ++m)
#pragma unroll
    for (int ks = 0; ks < 8; ++ks)
      av[m * 8 + ks] = *(const bf16x8*)(abase + ks * 4096 + kg * 1024 +
                                        (wv * 32 + m * 16 + l15) * 8);

  const unsigned char* bsrc = (const unsigned char*)ep + seg * 1048576;
  const float* hseg = h2 + seg * 2048;

  // stage B for g=0
#pragma unroll
  for (int i = 0; i < 2; ++i)
    cp16(bsrc + i * 4096 + wv * 1024 + lane * 16, &bLds[0][i * 4096 + wv * 1024]);

  float hv[8];
#pragma unroll
  for (int nf = 0; nf < 8; ++nf) hv[nf] = hseg[nf * 16 + l15];

  f32x4 acc[2][8];
#pragma unroll
  for (int m = 0; m < 2; ++m)
#pragma unroll
    for (int nf = 0; nf < 8; ++nf)
      acc[m][nf] = (f32x4){-hv[nf], -hv[nf], -hv[nf], -hv[nf]};

  float best[2][4];
#pragma unroll
  for (int m = 0; m < 2; ++m)
#pragma unroll
    for (int r = 0; r < 4; ++r) best[m][r] = -3.4e38f;

  __syncthreads();  // drains vmcnt(0): B g=0 staged

  for (int ch = 0; ch < 16; ++ch) {
    float hn[8];
    if (ch < 15) {
#pragma unroll
      for (int nf = 0; nf < 8; ++nf) hn[nf] = hseg[(ch + 1) * 128 + nf * 16 + l15];
    }
#pragma unroll
    for (int ks = 0; ks < 8; ++ks) {
      int g = ch * 8 + ks;
      int cur = g & 1;
      if (g < 127) {
#pragma unroll
        for (int i = 0; i < 2; ++i)
          cp16(bsrc + (g + 1) * 8192 + i * 4096 + wv * 1024 + lane * 16,
               &bLds[cur ^ 1][i * 4096 + wv * 1024]);
      }
      bf16x8 bv[8];
#pragma unroll
      for (int nf = 0; nf < 8; ++nf)
        bv[nf] = *(const bf16x8*)(&bLds[cur][kg * 2048 + (nf * 16 + l15) * 16]);
#pragma unroll
      for (int m = 0; m < 2; ++m)
#pragma unroll
        for (int nf = 0; nf < 8; ++nf)
          acc[m][nf] = __builtin_amdgcn_mfma_f32_16x16x32_bf16(
              av[m * 8 + ks], bv[nf], acc[m][nf], 0, 0, 0);
      __syncthreads();  // stage g+1 landed, all waves done with buf[cur]
    }
    // chunk epilogue: fold into running argmax (value packed with 11-bit col)
    int colbase = ch * 128 + l15;
#pragma unroll
    for (int m = 0; m < 2; ++m)
#pragma unroll
      for (int nf = 0; nf < 8; ++nf) {
        unsigned lcol = (unsigned)(colbase + nf * 16);
#pragma unroll
        for (int r = 0; r < 4; ++r) {
          unsigned p = (__float_as_uint(acc[m][nf][r]) & 0xFFFFF800u) | lcol;
          best[m][r] = fmaxf(best[m][r], __uint_as_float(p));
        }
      }
    if (ch < 15) {
#pragma unroll
      for (int m = 0; m < 2; ++m)
#pragma unroll
        for (int nf = 0; nf < 8; ++nf)
          acc[m][nf] = (f32x4){-hn[nf], -hn[nf], -hn[nf], -hn[nf]};
    }
  }

  // cross-lane (16 cols/group) argmax reduce, write per-(row,segment) partial
#pragma unroll
  for (int m = 0; m < 2; ++m)
#pragma unroll
    for (int r = 0; r < 4; ++r) {
      float bvv = best[m][r];
#pragma unroll
      for (int off = 1; off <= 8; off <<= 1) bvv = fmaxf(bvv, __shfl_xor(bvv, off));
      if (l15 == 0) {
        unsigned bits = __float_as_uint(bvv);
        int gidx = seg * 2048 + (int)(bits & 0x7FFu);
        int row = mt * 128 + wv * 32 + m * 16 + kg * 4 + r;
        partial[seg * 8192 + row] = make_int2((int)bits, gidx);
      }
    }
}

// ---------------- Reduce 8 segment partials -> idx -----------------------------
__global__ void k_reduce(const int2* __restrict__ partial, int* __restrict__ idxOut) {
  int row = blockIdx.x * 256 + threadIdx.x;
  float bb = -3.4e38f;
  int bi = 0;
#pragma unroll
  for (int s = 0; s < 8; ++s) {
    int2 p = partial[s * 8192 + row];
    float v = __int_as_float(p.x);
    if (v > bb) { bb = v; bi = p.y; }
  }
  idxOut[row] = bi;
}

// ---------------- Finalize: gather + straight-through + loss -------------------
__global__ void k_final(const float* __restrict__ z, const float* __restrict__ ew,
                        const int* __restrict__ idx, float* __restrict__ out) {
  int bidc = blockIdx.x;  // b*256 + c
  int b = bidc >> 8, c = bidc & 255;
  int t = threadIdx.x;
  int base = b * 262144 + c * 1024 + t * 4;
  float4 zv = *(const float4*)(z + base);
  int4 iv = *(const int4*)(idx + b * 1024 + t * 4);
  float4 ov;
  float ls = 0.0f;
  {
    float e0 = ew[iv.x * 256 + c]; float d0 = e0 - zv.x; ov.x = zv.x + d0; ls += d0 * d0;
    float e1 = ew[iv.y * 256 + c]; float d1 = e1 - zv.y; ov.y = zv.y + d1; ls += d1 * d1;
    float e2 = ew[iv.z * 256 + c]; float d2 = e2 - zv.z; ov.z = zv.z + d2; ls += d2 * d2;
    float e3 = ew[iv.w * 256 + c]; float d3 = e3 - zv.w; ov.w = zv.w + d3; ls += d3 * d3;
  }
  *(float4*)(out + base) = ov;
#pragma unroll
  for (int off = 32; off; off >>= 1) ls += __shfl_xor(ls, off);
  if ((t & 63) == 0) atomicAdd(out + 2097152, ls * (2.0f / 2097152.0f));
}

extern "C" void kernel_launch(void* const* d_in, const int* in_sizes, int n_in,
                              void* d_out, int out_size, void* d_ws, size_t ws_size,
                              hipStream_t stream) {
  const float* z = (const float*)d_in[0];
  const float* ew = (const float*)d_in[1];
  float* out = (float*)d_out;
  unsigned char* ws = (unsigned char*)d_ws;
  unsigned short* zp = (unsigned short*)ws;                           // 4 MB
  unsigned short* ep = (unsigned short*)(ws + (4u << 20));            // 8 MB
  float* h2 = (float*)(ws + (12u << 20));                             // 64 KB
  int2* partial = (int2*)(ws + (12u << 20) + 65536);                  // 512 KB
  int* idx = (int*)(ws + (12u << 20) + 65536 + 524288);               // 32 KB

  k_prep_z<<<512, 256, 0, stream>>>(z, zp);
  k_prep_e<<<512, 256, 0, stream>>>(ew, ep);
  k_norm<<<4096, 256, 0, stream>>>(ew, h2);
  k_main<<<dim3(8, 64), 256, 0, stream>>>(zp, ep, h2, partial);
  k_reduce<<<32, 256, 0, stream>>>(partial, idx);
  hipMemsetAsync(out + 2097152, 0, 4, stream);
  k_final<<<2048, 256, 0, stream>>>(z, ew, idx, out);
}

// Round 4
// 180.708 us; speedup vs baseline: 1.4529x; 1.4529x over previous
//
#include <hip/hip_runtime.h>
#include <hip/hip_bf16.h>
#include <stdint.h>

// VectorQuantizer on MI355X.
//   z: (8,256,32,32) f32  -> rows = 8192, K = 256
//   embed_w: (16384,256) f32
// out: z_q (2097152 f32) + loss (1 f32)

typedef __attribute__((ext_vector_type(8))) short bf16x8;
typedef __attribute__((ext_vector_type(8))) unsigned short ushort8v;
typedef __attribute__((ext_vector_type(4))) float f32x4;

__device__ __forceinline__ unsigned short f2bf(float f) {
  unsigned u = __float_as_uint(f);
  return (unsigned short)((u + 0x7FFFu + ((u >> 16) & 1u)) >> 16);
}

typedef const __attribute__((address_space(1))) unsigned char* gas1;
typedef __attribute__((address_space(3))) unsigned char* las3;
__device__ __forceinline__ void cp16(const void* g, void* l) {
  __builtin_amdgcn_global_load_lds((gas1)g, (las3)l, 16, 0, 0);
}

// ---------------- P1: z (8,256,1024) f32 -> z_prep blocked bf16 ----------------
// layout: [mt 64][ks 8][kg 4][row 128][8 elems]  (elem = ushort bf16)
__global__ void k_prep_z(const float* __restrict__ z, unsigned short* __restrict__ zp) {
  __shared__ float tile[32][129];
  int bid = blockIdx.x;
  int b = bid >> 6, ct = (bid >> 3) & 7, hwt = bid & 7;
  int t = threadIdx.x;
  const float* src = z + b * 262144 + ct * 32 * 1024 + hwt * 128;
#pragma unroll
  for (int it = 0; it < 16; ++it) {
    int e = it * 256 + t;
    int cl = e >> 7, hl = e & 127;
    tile[cl][hl] = src[cl * 1024 + hl];           // coalesced along hl
  }
  __syncthreads();
  int mt = b * 8 + hwt;
  unsigned short* dst = zp + mt * 32768 + ct * 4096;  // ct == kstep
#pragma unroll
  for (int it = 0; it < 2; ++it) {
    int cell = it * 256 + t;
    int kg = cell >> 7, r = cell & 127;
    ushort8v v;
#pragma unroll
    for (int j = 0; j < 8; ++j) v[j] = f2bf(tile[kg * 8 + j][r]);
    *(ushort8v*)(dst + cell * 8) = v;             // coalesced 16B
  }
}

// ------- P2: embed (16384,256) f32 -> e_prep blocked bf16, fused 0.5||e||^2 ----
// layout: [nb 128][ks 8][kg 4][col 128][8 elems]
__global__ void k_prep_e(const float* __restrict__ ew, unsigned short* __restrict__ ep,
                         float* __restrict__ h2) {
  int t = threadIdx.x;
  int n = blockIdx.x * 32 + (t >> 3);
  int nb = n >> 7, col = n & 127;
  float s = 0.0f;
#pragma unroll
  for (int it = 0; it < 4; ++it) {
    int cellk = (t & 7) + it * 8;
    const float4 x = *(const float4*)(ew + n * 256 + cellk * 8);
    const float4 y = *(const float4*)(ew + n * 256 + cellk * 8 + 4);
    s += x.x * x.x + x.y * x.y + x.z * x.z + x.w * x.w
       + y.x * y.x + y.y * y.y + y.z * y.z + y.w * y.w;
    int ks = cellk >> 2, kg = cellk & 3;
    ushort8v v;
    v[0] = f2bf(x.x); v[1] = f2bf(x.y); v[2] = f2bf(x.z); v[3] = f2bf(x.w);
    v[4] = f2bf(y.x); v[5] = f2bf(y.y); v[6] = f2bf(y.z); v[7] = f2bf(y.w);
    *(ushort8v*)(ep + nb * 32768 + ks * 4096 + kg * 1024 + col * 8) = v;
  }
#pragma unroll
  for (int off = 1; off <= 4; off <<= 1) s += __shfl_xor(s, off);
  if ((t & 7) == 0) h2[n] = 0.5f * s;
}

// ---------------- Main: fused GEMM + per-row argmax ----------------------------
// grid (8 seg, 64 mt), 256 threads. Wave w owns rows [w*32, w*32+32) of the
// 128-row M-tile, scanning all 2048 cols of its segment in 16 chunks of 128.
// A (128x256 bf16) lives in 16 reg fragments per lane; B double-buffered in LDS.
__global__ __launch_bounds__(256, 2) void k_main(
    const unsigned short* __restrict__ zp, const unsigned short* __restrict__ ep,
    const float* __restrict__ h2, int2* __restrict__ partial) {
  __shared__ unsigned char bLds[2][8192];
  int seg = blockIdx.x;   // 0..7  -> XCD-affine for L2 locality
  int mt = blockIdx.y;    // 0..63
  int t = threadIdx.x, wv = t >> 6, lane = t & 63;
  int l15 = lane & 15, kg = lane >> 4;

  // A tile -> registers: av[m*8+ks], 16B fragments
  bf16x8 av[16];
  const unsigned short* abase = zp + mt * 32768;
#pragma unroll
  for (int m = 0; m < 2; ++m)
#pragma unroll
    for (int ks = 0; ks < 8; ++ks)
      av[m * 8 + ks] = *(const bf16x8*)(abase + ks * 4096 + kg * 1024 +
                                        (wv * 32 + m * 16 + l15) * 8);

  const unsigned char* bsrc = (const unsigned char*)ep + seg * 1048576;
  const float* hseg = h2 + seg * 2048;

  // stage B for g=0
#pragma unroll
  for (int i = 0; i < 2; ++i)
    cp16(bsrc + i * 4096 + wv * 1024 + lane * 16, &bLds[0][i * 4096 + wv * 1024]);

  float hv[8];
#pragma unroll
  for (int nf = 0; nf < 8; ++nf) hv[nf] = hseg[nf * 16 + l15];

  f32x4 acc[2][8];
#pragma unroll
  for (int m = 0; m < 2; ++m)
#pragma unroll
    for (int nf = 0; nf < 8; ++nf)
      acc[m][nf] = (f32x4){-hv[nf], -hv[nf], -hv[nf], -hv[nf]};

  float best[2][4];
#pragma unroll
  for (int m = 0; m < 2; ++m)
#pragma unroll
    for (int r = 0; r < 4; ++r) best[m][r] = -3.4e38f;

  __syncthreads();  // drains vmcnt(0): B g=0 staged

  for (int ch = 0; ch < 16; ++ch) {
    float hn[8];
    if (ch < 15) {
#pragma unroll
      for (int nf = 0; nf < 8; ++nf) hn[nf] = hseg[(ch + 1) * 128 + nf * 16 + l15];
    }
#pragma unroll
    for (int ks = 0; ks < 8; ++ks) {
      int g = ch * 8 + ks;
      int cur = g & 1;
      if (g < 127) {
#pragma unroll
        for (int i = 0; i < 2; ++i)
          cp16(bsrc + (g + 1) * 8192 + i * 4096 + wv * 1024 + lane * 16,
               &bLds[cur ^ 1][i * 4096 + wv * 1024]);
      }
      bf16x8 bv[8];
#pragma unroll
      for (int nf = 0; nf < 8; ++nf)
        bv[nf] = *(const bf16x8*)(&bLds[cur][kg * 2048 + (nf * 16 + l15) * 16]);
#pragma unroll
      for (int m = 0; m < 2; ++m)
#pragma unroll
        for (int nf = 0; nf < 8; ++nf)
          acc[m][nf] = __builtin_amdgcn_mfma_f32_16x16x32_bf16(
              av[m * 8 + ks], bv[nf], acc[m][nf], 0, 0, 0);
      __syncthreads();  // stage g+1 landed, all waves done with buf[cur]
    }
    // chunk epilogue: fold into running argmax (value packed with 11-bit col)
    int colbase = ch * 128 + l15;
#pragma unroll
    for (int m = 0; m < 2; ++m)
#pragma unroll
      for (int nf = 0; nf < 8; ++nf) {
        unsigned lcol = (unsigned)(colbase + nf * 16);
#pragma unroll
        for (int r = 0; r < 4; ++r) {
          unsigned p = (__float_as_uint(acc[m][nf][r]) & 0xFFFFF800u) | lcol;
          best[m][r] = fmaxf(best[m][r], __uint_as_float(p));
        }
      }
    if (ch < 15) {
#pragma unroll
      for (int m = 0; m < 2; ++m)
#pragma unroll
        for (int nf = 0; nf < 8; ++nf)
          acc[m][nf] = (f32x4){-hn[nf], -hn[nf], -hn[nf], -hn[nf]};
    }
  }

  // cross-lane (16 cols/group) argmax reduce, write per-(row,segment) partial
#pragma unroll
  for (int m = 0; m < 2; ++m)
#pragma unroll
    for (int r = 0; r < 4; ++r) {
      float bvv = best[m][r];
#pragma unroll
      for (int off = 1; off <= 8; off <<= 1) bvv = fmaxf(bvv, __shfl_xor(bvv, off));
      if (l15 == 0) {
        unsigned bits = __float_as_uint(bvv);
        int gidx = seg * 2048 + (int)(bits & 0x7FFu);
        int row = mt * 128 + wv * 32 + m * 16 + kg * 4 + r;
        partial[seg * 8192 + row] = make_int2((int)bits, gidx);
      }
    }
}

// -------- Reduce 8 segment partials -> winning code; gather its row ------------
// 4 rows/block (one per wave). All 64 lanes redundantly reduce (broadcast
// loads), then copy the 1 KB code row coalesced into pixel-major `rows`.
__global__ void k_rg(const int2* __restrict__ partial, const float* __restrict__ ew,
                     float* __restrict__ rows) {
  int row = blockIdx.x * 4 + (threadIdx.x >> 6);
  int lane = threadIdx.x & 63;
  float bb = -3.4e38f;
  int bi = 0;
#pragma unroll
  for (int s = 0; s < 8; ++s) {
    int2 p = partial[s * 8192 + row];
    float v = __int_as_float(p.x);
    if (v > bb) { bb = v; bi = p.y; }
  }
  float4 v = *(const float4*)(ew + bi * 256 + lane * 4);
  *(float4*)(rows + row * 256 + lane * 4) = v;
}

// -------- Transpose rows (pixel-major) -> out (channel-major), fused loss ------
// STE forward value == gathered code exactly, so out = transpose(rows);
// z only feeds the loss, read coalesced in channel-major layout.
__global__ void k_out(const float* __restrict__ rows, const float* __restrict__ z,
                      float* __restrict__ out) {
  __shared__ float tile[32][132];
  int bid = blockIdx.x;
  int b = bid >> 6, hwt = (bid >> 3) & 7, ct = bid & 7;
  int t = threadIdx.x;
  int hw0 = hwt * 128, c0 = ct * 32;
  const float* rbase = rows + (b * 1024 + hw0) * 256 + c0;
#pragma unroll
  for (int it = 0; it < 4; ++it) {
    int p = it * 32 + (t >> 3);
    int c = (t & 7) * 4;
    float4 v = *(const float4*)(rbase + p * 256 + c);
    tile[c][p] = v.x; tile[c + 1][p] = v.y; tile[c + 2][p] = v.z; tile[c + 3][p] = v.w;
  }
  __syncthreads();
  float ls = 0.0f;
  int obase = b * 262144 + c0 * 1024 + hw0;
#pragma unroll
  for (int it = 0; it < 4; ++it) {
    int c = it * 8 + (t >> 5);
    int p = (t & 31) * 4;
    float4 q = *(const float4*)(&tile[c][p]);
    float4 zv = *(const float4*)(z + obase + c * 1024 + p);
    float dx = q.x - zv.x, dy = q.y - zv.y, dz = q.z - zv.z, dw = q.w - zv.w;
    ls += dx * dx + dy * dy + dz * dz + dw * dw;
    *(float4*)(out + obase + c * 1024 + p) = q;
  }
#pragma unroll
  for (int off = 32; off; off >>= 1) ls += __shfl_xor(ls, off);
  if ((t & 63) == 0) atomicAdd(out + 2097152, ls * (2.0f / 2097152.0f));
}

extern "C" void kernel_launch(void* const* d_in, const int* in_sizes, int n_in,
                              void* d_out, int out_size, void* d_ws, size_t ws_size,
                              hipStream_t stream) {
  const float* z = (const float*)d_in[0];
  const float* ew = (const float*)d_in[1];
  float* out = (float*)d_out;
  unsigned char* ws = (unsigned char*)d_ws;
  unsigned short* zp = (unsigned short*)ws;                           // 4 MB
  unsigned short* ep = (unsigned short*)(ws + (4u << 20));            // 8 MB
  float* h2 = (float*)(ws + (12u << 20));                             // 64 KB
  int2* partial = (int2*)(ws + (12u << 20) + 65536);                  // 512 KB
  float* rows = (float*)(ws + (13u << 20));                           // 8 MB

  k_prep_z<<<512, 256, 0, stream>>>(z, zp);
  k_prep_e<<<512, 256, 0, stream>>>(ew, ep, h2);
  k_main<<<dim3(8, 64), 256, 0, stream>>>(zp, ep, h2, partial);
  k_rg<<<2048, 256, 0, stream>>>(partial, ew, rows);
  hipMemsetAsync(out + 2097152, 0, 4, stream);
  k_out<<<512, 256, 0, stream>>>(rows, z, out);
}

// Round 5
// 176.354 us; speedup vs baseline: 1.4887x; 1.0247x over previous
//
#include <hip/hip_runtime.h>
#include <hip/hip_bf16.h>
#include <stdint.h>

// VectorQuantizer on MI355X.
//   z: (8,256,32,32) f32  -> rows = 8192, K = 256
//   embed_w: (16384,256) f32
// out: z_q (2097152 f32) + loss (1 f32)
// Pipeline: k_prep (z->bf16 blocked, e->bf16 blocked + 0.5||e||^2 + loss=0)
//        -> k_main (fused GEMM+argmax, 16 segs x 64 mtiles, BK=64/barrier)
//        -> k_fin  (reduce 16 partials -> gather code slice -> transpose -> out+loss)

typedef __attribute__((ext_vector_type(8))) short bf16x8;
typedef __attribute__((ext_vector_type(8))) unsigned short ushort8v;
typedef __attribute__((ext_vector_type(4))) float f32x4;

__device__ __forceinline__ unsigned short f2bf(float f) {
  unsigned u = __float_as_uint(f);
  return (unsigned short)((u + 0x7FFFu + ((u >> 16) & 1u)) >> 16);
}

typedef const __attribute__((address_space(1))) unsigned char* gas1;
typedef __attribute__((address_space(3))) unsigned char* las3;
__device__ __forceinline__ void cp16(const void* g, void* l) {
  __builtin_amdgcn_global_load_lds((gas1)g, (las3)l, 16, 0, 0);
}

// ---------------- P: fused prep ------------------------------------------------
// blocks 0..511: z (8,256,1024) f32 -> zp blocked bf16 [mt 64][ks 8][kg 4][row 128][8]
// blocks 512..1023: ew (16384,256) f32 -> ep blocked bf16 [nb 128][ks 8][kg 4][col 128][8]
//                   + h2[n] = 0.5||e_n||^2 ; block 512 t0 zeroes the loss slot.
__global__ void k_prep(const float* __restrict__ z, const float* __restrict__ ew,
                       unsigned short* __restrict__ zp, unsigned short* __restrict__ ep,
                       float* __restrict__ h2, float* __restrict__ out) {
  __shared__ float tile[32][132];
  int bid = blockIdx.x;
  int t = threadIdx.x;
  if (bid < 512) {
    int b = bid >> 6, ct = (bid >> 3) & 7, hwt = bid & 7;
    const float* src = z + b * 262144 + ct * 32768 + hwt * 128;
#pragma unroll
    for (int it = 0; it < 4; ++it) {
      int cell = it * 1024 + t * 4;
      int cl = cell >> 7, hl = cell & 127;
      float4 v = *(const float4*)(src + cl * 1024 + hl);   // coalesced float4
      *(float4*)(&tile[cl][hl]) = v;
    }
    __syncthreads();
    int mt = b * 8 + hwt;
    unsigned short* dst = zp + mt * 32768 + ct * 4096;     // ct == kstep
#pragma unroll
    for (int it = 0; it < 2; ++it) {
      int cell = it * 256 + t;
      int kg = cell >> 7, r = cell & 127;
      ushort8v v;
#pragma unroll
      for (int j = 0; j < 8; ++j) v[j] = f2bf(tile[kg * 8 + j][r]);
      *(ushort8v*)(dst + cell * 8) = v;                    // coalesced 16B
    }
  } else {
    if (bid == 512 && t == 0) out[2097152] = 0.0f;
    int n = (bid - 512) * 32 + (t >> 3);
    int nb = n >> 7, col = n & 127;
    float s = 0.0f;
#pragma unroll
    for (int it = 0; it < 4; ++it) {
      int cellk = (t & 7) + it * 8;
      const float4 x = *(const float4*)(ew + n * 256 + cellk * 8);
      const float4 y = *(const float4*)(ew + n * 256 + cellk * 8 + 4);
      s += x.x * x.x + x.y * x.y + x.z * x.z + x.w * x.w
         + y.x * y.x + y.y * y.y + y.z * y.z + y.w * y.w;
      int ks = cellk >> 2, kg = cellk & 3;
      ushort8v v;
      v[0] = f2bf(x.x); v[1] = f2bf(x.y); v[2] = f2bf(x.z); v[3] = f2bf(x.w);
      v[4] = f2bf(y.x); v[5] = f2bf(y.y); v[6] = f2bf(y.z); v[7] = f2bf(y.w);
      *(ushort8v*)(ep + nb * 32768 + ks * 4096 + kg * 1024 + col * 8) = v;
    }
#pragma unroll
    for (int off = 1; off <= 4; off <<= 1) s += __shfl_xor(s, off);
    if ((t & 7) == 0) h2[n] = 0.5f * s;
  }
}

// ---------------- Main: fused GEMM + per-row argmax ----------------------------
// grid (16 seg, 64 mt), 256 thr. seg = 1024 cols; per block 8 col-chunks of 128.
// K-step per barrier = 64 (16 KB staged, 32 MFMA/barrier). A in regs, B dbuf LDS.
__global__ __launch_bounds__(256, 3) void k_main(
    const unsigned short* __restrict__ zp, const unsigned short* __restrict__ ep,
    const float* __restrict__ h2, int2* __restrict__ partial) {
  __shared__ unsigned char bLds[2][16384];
  int seg = blockIdx.x;   // 0..15 -> XCD seg%8 (2 B-panels of 0.5 MB per XCD L2)
  int mt = blockIdx.y;    // 0..63
  int t = threadIdx.x, wv = t >> 6, lane = t & 63;
  int l15 = lane & 15, kg = lane >> 4;

  // A tile -> registers: av[m*8+ks], 16B fragments
  bf16x8 av[16];
  const unsigned short* abase = zp + mt * 32768;
#pragma unroll
  for (int m = 0; m < 2; ++m)
#pragma unroll
    for (int ks = 0; ks < 8; ++ks)
      av[m * 8 + ks] = *(const bf16x8*)(abase + ks * 4096 + kg * 1024 +
                                        (wv * 32 + m * 16 + l15) * 8);

  const unsigned char* bsrc = (const unsigned char*)ep + seg * 524288;
  const float* hseg = h2 + seg * 1024;

  // stage step 0 (16 KB)
#pragma unroll
  for (int i = 0; i < 4; ++i)
    cp16(bsrc + i * 4096 + wv * 1024 + lane * 16, &bLds[0][i * 4096 + wv * 1024]);

  f32x4 acc[2][8];
  float best[2][4];
#pragma unroll
  for (int m = 0; m < 2; ++m)
#pragma unroll
    for (int r = 0; r < 4; ++r) best[m][r] = -3.4e38f;

  __syncthreads();  // drains vmcnt(0): step 0 staged

  // 32 steps: step s = nb*4 + ph covers cols [nb*128,nb*128+128), k [ph*64, ph*64+64)
#pragma unroll 4
  for (int s = 0; s < 32; ++s) {
    int cur = s & 1;
    if (s < 31) {
#pragma unroll
      for (int i = 0; i < 4; ++i)
        cp16(bsrc + (s + 1) * 16384 + i * 4096 + wv * 1024 + lane * 16,
             &bLds[cur ^ 1][i * 4096 + wv * 1024]);
    }
    int nb = s >> 2, ph = s & 3;
    if (ph == 0) {
#pragma unroll
      for (int nf = 0; nf < 8; ++nf) {
        float h = hseg[nb * 128 + nf * 16 + l15];
        acc[0][nf] = (f32x4){-h, -h, -h, -h};
        acc[1][nf] = acc[0][nf];
      }
    }
    __builtin_amdgcn_s_setprio(1);
#pragma unroll
    for (int k2 = 0; k2 < 2; ++k2) {
      bf16x8 bv[8];
#pragma unroll
      for (int nf = 0; nf < 8; ++nf)
        bv[nf] = *(const bf16x8*)(&bLds[cur][k2 * 8192 + kg * 2048 + (nf * 16 + l15) * 16]);
#pragma unroll
      for (int m = 0; m < 2; ++m)
#pragma unroll
        for (int nf = 0; nf < 8; ++nf)
          acc[m][nf] = __builtin_amdgcn_mfma_f32_16x16x32_bf16(
              av[m * 8 + ph * 2 + k2], bv[nf], acc[m][nf], 0, 0, 0);
    }
    __builtin_amdgcn_s_setprio(0);
    if (ph == 3) {
      // chunk done: fold into running argmax (value packed with 11-bit col)
      int colbase = nb * 128 + l15;
#pragma unroll
      for (int m = 0; m < 2; ++m)
#pragma unroll
        for (int nf = 0; nf < 8; ++nf) {
          unsigned lcol = (unsigned)(colbase + nf * 16);
#pragma unroll
          for (int r = 0; r < 4; ++r) {
            unsigned p = (__float_as_uint(acc[m][nf][r]) & 0xFFFFF800u) | lcol;
            best[m][r] = fmaxf(best[m][r], __uint_as_float(p));
          }
        }
    }
    __syncthreads();
  }

  // cross-lane (16 cols/group) argmax reduce, write per-(row,segment) partial
#pragma unroll
  for (int m = 0; m < 2; ++m)
#pragma unroll
    for (int r = 0; r < 4; ++r) {
      float bvv = best[m][r];
#pragma unroll
      for (int off = 1; off <= 8; off <<= 1) bvv = fmaxf(bvv, __shfl_xor(bvv, off));
      if (l15 == 0) {
        unsigned bits = __float_as_uint(bvv);
        int gidx = seg * 1024 + (int)(bits & 0x7FFu);
        int row = mt * 128 + wv * 32 + m * 16 + kg * 4 + r;
        partial[seg * 8192 + row] = make_int2((int)bits, gidx);
      }
    }
}

// -------- Final: reduce partials -> gather code slice -> transpose -> out+loss --
// block (b, hwt, ct) covers 128 pixels x 32 channels. STE forward == gathered
// code exactly; z only feeds the loss (coalesced channel-major read).
__global__ void k_fin(const int2* __restrict__ partial, const float* __restrict__ ew,
                      const float* __restrict__ z, float* __restrict__ out) {
  __shared__ float tile[32][132];
  __shared__ int codeIdx[128];
  int bid = blockIdx.x;
  int b = bid >> 6, hwt = (bid >> 3) & 7, ct = bid & 7;
  int t = threadIdx.x;
  int rowbase = b * 1024 + hwt * 128;
  if (t < 128) {
    int row = rowbase + t;
    float bb = -3.4e38f;
    int bi = 0;
#pragma unroll
    for (int s = 0; s < 16; ++s) {
      int2 p = partial[s * 8192 + row];
      float v = __int_as_float(p.x);
      if (v > bb) { bb = v; bi = p.y; }
    }
    codeIdx[t] = bi;
  }
  __syncthreads();
  int c0 = ct * 32;
  {
    int p = t >> 1, half = t & 1;
    const float* er = ew + codeIdx[p] * 256 + c0 + half * 16;
#pragma unroll
    for (int j = 0; j < 4; ++j) {
      float4 v = *(const float4*)(er + j * 4);
      int c = half * 16 + j * 4;
      tile[c][p] = v.x; tile[c + 1][p] = v.y; tile[c + 2][p] = v.z; tile[c + 3][p] = v.w;
    }
  }
  __syncthreads();
  float ls = 0.0f;
  int obase = b * 262144 + c0 * 1024 + hwt * 128;
#pragma unroll
  for (int it = 0; it < 4; ++it) {
    int c = it * 8 + (t >> 5);
    int p = (t & 31) * 4;
    float4 q = *(const float4*)(&tile[c][p]);
    float4 zv = *(const float4*)(z + obase + c * 1024 + p);
    float dx = q.x - zv.x, dy = q.y - zv.y, dz = q.z - zv.z, dw = q.w - zv.w;
    ls += dx * dx + dy * dy + dz * dz + dw * dw;
    *(float4*)(out + obase + c * 1024 + p) = q;
  }
#pragma unroll
  for (int off = 32; off; off >>= 1) ls += __shfl_xor(ls, off);
  if ((t & 63) == 0) atomicAdd(out + 2097152, ls * (2.0f / 2097152.0f));
}

extern "C" void kernel_launch(void* const* d_in, const int* in_sizes, int n_in,
                              void* d_out, int out_size, void* d_ws, size_t ws_size,
                              hipStream_t stream) {
  const float* z = (const float*)d_in[0];
  const float* ew = (const float*)d_in[1];
  float* out = (float*)d_out;
  unsigned char* ws = (unsigned char*)d_ws;
  unsigned short* zp = (unsigned short*)ws;                           // 4 MB
  unsigned short* ep = (unsigned short*)(ws + (4u << 20));            // 8 MB
  float* h2 = (float*)(ws + (12u << 20));                             // 64 KB
  int2* partial = (int2*)(ws + (12u << 20) + 65536);                  // 1 MB

  k_prep<<<1024, 256, 0, stream>>>(z, ew, zp, ep, h2, out);
  k_main<<<dim3(16, 64), 256, 0, stream>>>(zp, ep, h2, partial);
  k_fin<<<512, 256, 0, stream>>>(partial, ew, z, out);
}